// Round 5
// baseline (13.609 us; speedup 1.0000x reference)
//
#include <hip/hip_runtime.h>

// DEQ solver, closed-form: out = sign(x0) * max(|x0| - lam, 0).
// Pure streaming, 50.3 MB traffic. 2048 blocks x 256 threads x 3
// float4/thread (exact for n=6291456), loads issued back-to-back for MLP.
// nt on BOTH streams: stores proven +3us (R3 vs R4); loads are
// read-once-per-dispatch so L2 allocation is useless.

typedef float f32x4 __attribute__((ext_vector_type(4)));

__device__ __forceinline__ f32x4 soft4(f32x4 v, float lam) {
    f32x4 r;
    r.x = copysignf(fmaxf(fabsf(v.x) - lam, 0.0f), v.x);
    r.y = copysignf(fmaxf(fabsf(v.y) - lam, 0.0f), v.y);
    r.z = copysignf(fmaxf(fabsf(v.z) - lam, 0.0f), v.z);
    r.w = copysignf(fmaxf(fabsf(v.w) - lam, 0.0f), v.w);
    return r;
}

__global__ void __launch_bounds__(256)
deq_soft3_kernel(const f32x4* __restrict__ x4,
                 const float* __restrict__ lam_p,
                 f32x4* __restrict__ out4) {
    const float lam = lam_p[0];
    const int tid = blockIdx.x * 256 + threadIdx.x;
    const int stride = 2048 * 256;

    // three independent nt loads in flight
    f32x4 v0 = __builtin_nontemporal_load(&x4[tid]);
    f32x4 v1 = __builtin_nontemporal_load(&x4[tid + stride]);
    f32x4 v2 = __builtin_nontemporal_load(&x4[tid + 2 * stride]);

    f32x4 r0 = soft4(v0, lam);
    f32x4 r1 = soft4(v1, lam);
    f32x4 r2 = soft4(v2, lam);

    __builtin_nontemporal_store(r0, &out4[tid]);
    __builtin_nontemporal_store(r1, &out4[tid + stride]);
    __builtin_nontemporal_store(r2, &out4[tid + 2 * stride]);
}

__global__ void __launch_bounds__(256)
deq_soft_fallback(const f32x4* __restrict__ x4,
                  const float* __restrict__ lam_p,
                  f32x4* __restrict__ out4, int n4) {
    const float lam = lam_p[0];
    int idx = blockIdx.x * blockDim.x + threadIdx.x;
    const int stride = gridDim.x * blockDim.x;
    for (; idx < n4; idx += stride) {
        f32x4 v = __builtin_nontemporal_load(&x4[idx]);
        __builtin_nontemporal_store(soft4(v, lam), &out4[idx]);
    }
}

extern "C" void kernel_launch(void* const* d_in, const int* in_sizes, int n_in,
                              void* d_out, int out_size, void* d_ws, size_t ws_size,
                              hipStream_t stream) {
    const float* x0  = (const float*)d_in[0];   // (8,3,512,512) fp32
    const float* lam = (const float*)d_in[2];   // scalar fp32
    float* out = (float*)d_out;

    const int n  = in_sizes[0];
    const int n4 = n >> 2;

    if (n4 == 2048 * 256 * 3) {
        deq_soft3_kernel<<<2048, 256, 0, stream>>>(
            (const f32x4*)x0, lam, (f32x4*)out);
    } else {
        const int block = 256;
        int grid = (n4 + block - 1) / block;
        if (grid > 2048) grid = 2048;
        deq_soft_fallback<<<grid, block, 0, stream>>>(
            (const f32x4*)x0, lam, (f32x4*)out, n4);
    }
}

// Round 6
// 10.634 us; speedup vs baseline: 1.2798x; 1.2798x over previous
//
#include <hip/hip_runtime.h>

// DEQ solver, closed-form: out = sign(x0) * max(|x0| - lam, 0).
// Pure streaming, 50.3 MB traffic. 2048 blocks x 256 threads x 3
// float4/thread (exact for n=6291456), loads issued back-to-back for MLP.
// Proven-optimal cache policy (R3/R4/R5 matrix):
//   loads  CACHEABLE — input constant across replays, L3-resident (25 MB)
//   stores NT        — output write-once-read-never; avoids allocate cost
// (nt loads: +3.2us regression; cacheable stores: +2.9us regression)

typedef float f32x4 __attribute__((ext_vector_type(4)));

__device__ __forceinline__ f32x4 soft4(f32x4 v, float lam) {
    f32x4 r;
    r.x = copysignf(fmaxf(fabsf(v.x) - lam, 0.0f), v.x);
    r.y = copysignf(fmaxf(fabsf(v.y) - lam, 0.0f), v.y);
    r.z = copysignf(fmaxf(fabsf(v.z) - lam, 0.0f), v.z);
    r.w = copysignf(fmaxf(fabsf(v.w) - lam, 0.0f), v.w);
    return r;
}

__global__ void __launch_bounds__(256)
deq_soft3_kernel(const f32x4* __restrict__ x4,
                 const float* __restrict__ lam_p,
                 f32x4* __restrict__ out4) {
    const float lam = lam_p[0];
    const int tid = blockIdx.x * 256 + threadIdx.x;
    const int stride = 2048 * 256;

    // three independent loads in flight
    f32x4 v0 = x4[tid];
    f32x4 v1 = x4[tid + stride];
    f32x4 v2 = x4[tid + 2 * stride];

    f32x4 r0 = soft4(v0, lam);
    f32x4 r1 = soft4(v1, lam);
    f32x4 r2 = soft4(v2, lam);

    __builtin_nontemporal_store(r0, &out4[tid]);
    __builtin_nontemporal_store(r1, &out4[tid + stride]);
    __builtin_nontemporal_store(r2, &out4[tid + 2 * stride]);
}

__global__ void __launch_bounds__(256)
deq_soft_fallback(const f32x4* __restrict__ x4,
                  const float* __restrict__ lam_p,
                  f32x4* __restrict__ out4, int n4) {
    const float lam = lam_p[0];
    int idx = blockIdx.x * blockDim.x + threadIdx.x;
    const int stride = gridDim.x * blockDim.x;
    for (; idx < n4; idx += stride) {
        f32x4 v = x4[idx];
        __builtin_nontemporal_store(soft4(v, lam), &out4[idx]);
    }
}

extern "C" void kernel_launch(void* const* d_in, const int* in_sizes, int n_in,
                              void* d_out, int out_size, void* d_ws, size_t ws_size,
                              hipStream_t stream) {
    const float* x0  = (const float*)d_in[0];   // (8,3,512,512) fp32
    const float* lam = (const float*)d_in[2];   // scalar fp32
    float* out = (float*)d_out;

    const int n  = in_sizes[0];
    const int n4 = n >> 2;

    if (n4 == 2048 * 256 * 3) {
        deq_soft3_kernel<<<2048, 256, 0, stream>>>(
            (const f32x4*)x0, lam, (f32x4*)out);
    } else {
        const int block = 256;
        int grid = (n4 + block - 1) / block;
        if (grid > 2048) grid = 2048;
        deq_soft_fallback<<<grid, block, 0, stream>>>(
            (const f32x4*)x0, lam, (f32x4*)out, n4);
    }
}